// Round 13
// baseline (2166.399 us; speedup 1.0000x reference)
//
#include <hip/hip_runtime.h>
#include <math.h>

#define FF 2048
#define NL 12
#define NB 16
#define TT 32
#define EPS 1e-5f
#define LOG2E 1.44269504088896f

typedef float v2f __attribute__((ext_vector_type(2)));
__device__ __forceinline__ v2f mk2(float x){ v2f r; r.x = x; r.y = x; return r; }

// ---------------------------------------------------------------------------
// Prepack into d_ws as w_all[24][4096] float4, f-PAIRED for packed math:
//   [0..1023]    A0[fp] = {w0[2fp],w0[2fp+1], w1[2fp],w1[2fp+1]}
//   [1024..2047] A1[fp] = {w2[2fp],w2[2fp+1], b[2fp], b[2fp+1]}
//   [2048..3071] C0[fp] = {u0[2fp],u0[2fp+1], u1[2fp],u1[2fp+1]}
//   [3072..4095] C1[fp] = {u2[2fp],u2[2fp+1], 0, 0}
// ---------------------------------------------------------------------------
__global__ __launch_bounds__(256) void prepack_kernel(
    const float* __restrict__ enc_l1_w, const float* __restrict__ enc_l1_b,
    const float* __restrict__ enc_l2_w,
    const float* __restrict__ dec_l1_w, const float* __restrict__ dec_l1_b,
    const float* __restrict__ dec_l2_w,
    float4* __restrict__ w_all)
{
    int idx = blockIdx.x * blockDim.x + threadIdx.x;
    if (idx >= 24 * 1024) return;
    int lay = idx >> 10;
    int fp  = idx & 1023;
    int f0  = 2*fp, f1 = 2*fp + 1;
    const float *w1, *b1, *w2;
    if (lay < NL) {
        w1 = enc_l1_w + (size_t)lay * FF * 3;
        b1 = enc_l1_b + (size_t)lay * FF;
        w2 = enc_l2_w + (size_t)lay * 3 * FF;
    } else {
        int l = lay - NL;
        w1 = dec_l1_w + (size_t)l * FF * 3;
        b1 = dec_l1_b + (size_t)l * FF;
        w2 = dec_l2_w + (size_t)l * 3 * FF;
    }
    float4* base = w_all + (size_t)lay * 4096;
    base[fp]        = make_float4(w1[f0*3+0], w1[f1*3+0], w1[f0*3+1], w1[f1*3+1]);
    base[1024 + fp] = make_float4(w1[f0*3+2], w1[f1*3+2], b1[f0],     b1[f1]);
    base[2048 + fp] = make_float4(w2[f0],     w2[f1],     w2[FF+f0],  w2[FF+f1]);
    base[3072 + fp] = make_float4(w2[2*FF+f0], w2[2*FF+f1], 0.f, 0.f);
}

// ---------------------------------------------------------------------------
// Main kernel: one block per batch element, 1024 threads (16 waves).
// ---------------------------------------------------------------------------
struct __align__(16) SharedMem {
    float4 wbuf[2][4096];  // double-buffered layer weights (128 KB)
    float4 x4[TT];         // activations
    float4 fred[TT][3];    // FFN partials: [t][d] = 4 per-wave-group sums
    float4 outst[TT];      // decoder predictions
    float4 mem4[TT];       // encoder output
    float  kk[3][TT];      // self-attn keys, head-major
    float  vv[3][TT];      // self-attn values
    float  oo[TT][3];      // SA attention outputs
    float  oo2[TT][3];     // CA attention outputs
    float  ck[NL][3][TT];  // cross-attn keys per decoder layer
    float  cv[NL][3][TT];  // cross-attn values
};

__device__ __forceinline__ void ln3s(float y0, float y1, float y2,
    const float* __restrict__ w, const float* __restrict__ b,
    float& o0, float& o1, float& o2)
{
    float m  = (y0 + y1 + y2) * (1.0f / 3.0f);
    float d0 = y0 - m, d1 = y1 - m, d2 = y2 - m;
    float v  = (d0*d0 + d1*d1 + d2*d2) * (1.0f / 3.0f);
    float r  = __builtin_amdgcn_rsqf(v + EPS);
    o0 = d0 * r * w[0] + b[0];
    o1 = d1 * r * w[1] + b[1];
    o2 = d2 * r * w[2] + b[2];
}

template<int CTRL>
__device__ __forceinline__ float dpp_add(float v)
{
    int sh = __builtin_amdgcn_update_dpp(0, __float_as_int(v), CTRL, 0xF, 0xF, true);
    return v + __int_as_float(sh);
}

__device__ __forceinline__ float wave_sum64(float v)
{
    v = dpp_add<0x111>(v);
    v = dpp_add<0x112>(v);
    v = dpp_add<0x114>(v);
    v = dpp_add<0x118>(v);
    v = dpp_add<0x142>(v);
    v = dpp_add<0x143>(v);
    return v;   // valid in lane 63
}

__device__ __forceinline__ float sum4(float4 r)
{
    return (r.x + r.y) + (r.z + r.w);
}

// Halved-range softmax-attention: lanes 0-31 handle keys 0..15, lanes 32-63
// keys 16..31; partials combined via shfl_xor(32). qs has log2e folded.
// Split accumulators halve the serial fp-add chain.
template<bool MASK>
__device__ __forceinline__ float attn_half(float qs,
    const float* __restrict__ k, const float* __restrict__ v,
    int half, int ntok, int rep, float repw)
{
    const float4* k4 = (const float4*)k;
    const float4* v4 = (const float4*)v;
    float den0 = 0.f, den1 = 0.f, nv0 = 0.f, nv1 = 0.f;
    #pragma unroll
    for (int jb = 0; jb < 4; ++jb) {
        float4 kq = k4[half*4 + jb];
        float4 vq = v4[half*4 + jb];
        const float kj[4] = {kq.x, kq.y, kq.z, kq.w};
        const float vj[4] = {vq.x, vq.y, vq.z, vq.w};
        #pragma unroll
        for (int u = 0; u < 4; ++u) {
            float w = exp2f(qs * kj[u]);
            if (MASK) {
                const int j = half*16 + jb*4 + u;
                w = (j < ntok) ? w : 0.f;
                w = (j == rep) ? w * repw : w;
            }
            if (jb & 1) { den1 += w; nv1 = fmaf(w, vj[u], nv1); }
            else        { den0 += w; nv0 = fmaf(w, vj[u], nv0); }
        }
    }
    float den = den0 + den1;
    float nv  = nv0 + nv1;
    den += __shfl_xor(den, 32, 64);
    nv  += __shfl_xor(nv , 32, 64);
    return nv * __builtin_amdgcn_rcpf(den);
}

// FFN: 4 token groups x 256 f-lanes, 4 f-pairs per thread, packed fp32 math
// (v_pk_fma_f32), weights from LDS, DPP reduction + lane-63 store.
// NII = exact ceil(ntok/4) (1..8) — no token round-up waste.
template<int NII>
__device__ __forceinline__ void ffn_body(SharedMem& s, int tid,
    const float4* __restrict__ wb, int ntok)
{
    const int flane = tid & 255;
    const int g     = tid >> 8;
    const int w4    = (tid >> 6) & 3;
    const int lane  = tid & 63;
    const v2f z2 = {0.f, 0.f};
    float X0[NII], X1[NII], X2[NII];
    v2f ac0[NII], ac1[NII], ac2[NII];
    #pragma unroll
    for (int ii = 0; ii < NII; ++ii) {
        float4 xt = s.x4[g + 4*ii];
        X0[ii] = xt.x; X1[ii] = xt.y; X2[ii] = xt.z;
        ac0[ii] = z2; ac1[ii] = z2; ac2[ii] = z2;
    }
    #pragma unroll
    for (int jp = 0; jp < 4; ++jp) {
        const int fp = flane + 256*jp;
        float4 A0 = wb[fp], A1 = wb[1024+fp];
        float4 C0 = wb[2048+fp], C1 = wb[3072+fp];
        v2f ax = {A0.x, A0.y}, ay = {A0.z, A0.w};
        v2f az = {A1.x, A1.y}, ab = {A1.z, A1.w};
        v2f cx = {C0.x, C0.y}, cy = {C0.z, C0.w};
        v2f cz = {C1.x, C1.y};
        #pragma unroll
        for (int ii = 0; ii < NII; ++ii) {
            v2f h2 = __builtin_elementwise_fma(ax, mk2(X0[ii]),
                     __builtin_elementwise_fma(ay, mk2(X1[ii]),
                     __builtin_elementwise_fma(az, mk2(X2[ii]), ab)));
            h2 = __builtin_elementwise_max(h2, z2);
            ac0[ii] = __builtin_elementwise_fma(cx, h2, ac0[ii]);
            ac1[ii] = __builtin_elementwise_fma(cy, h2, ac1[ii]);
            ac2[ii] = __builtin_elementwise_fma(cz, h2, ac2[ii]);
        }
    }
    #pragma unroll
    for (int ii = 0; ii < NII; ++ii) {
        const int t = g + 4*ii;
        float r0 = wave_sum64(ac0[ii].x + ac0[ii].y);
        float r1 = wave_sum64(ac1[ii].x + ac1[ii].y);
        float r2 = wave_sum64(ac2[ii].x + ac2[ii].y);
        if (lane == 63 && t < ntok) {
            ((float*)&s.fred[t][0])[w4] = r0;
            ((float*)&s.fred[t][1])[w4] = r1;
            ((float*)&s.fred[t][2])[w4] = r2;
        }
    }
}

__device__ __forceinline__ void ffn_dispatch(SharedMem& s, int tid,
    const float4* __restrict__ wb, int ntok)
{
    switch ((ntok + 3) >> 2) {
        case 1: ffn_body<1>(s, tid, wb, ntok); break;
        case 2: ffn_body<2>(s, tid, wb, ntok); break;
        case 3: ffn_body<3>(s, tid, wb, ntok); break;
        case 4: ffn_body<4>(s, tid, wb, ntok); break;
        case 5: ffn_body<5>(s, tid, wb, ntok); break;
        case 6: ffn_body<6>(s, tid, wb, ntok); break;
        case 7: ffn_body<7>(s, tid, wb, ntok); break;
        default: ffn_body<8>(s, tid, wb, ntok); break;
    }
}

// One transformer layer (R11 phase structure, unchanged).
template<bool HAS_CA, bool MASK_SA>
__device__ __forceinline__ void run_layer(SharedMem& s, int tid,
    int ntok, int rep, float repw, int do_combine, int p,
    const float4* __restrict__ nw,
    const float* __restrict__ saw, const float* __restrict__ sab,
    const float* __restrict__ saow, const float* __restrict__ saob,
    const float* __restrict__ n1w, const float* __restrict__ n1b,
    const float* __restrict__ caw, const float* __restrict__ cab,
    const float* __restrict__ caow, const float* __restrict__ caob,
    const float* __restrict__ n2w, const float* __restrict__ n2b,
    const float* __restrict__ ckh, const float* __restrict__ cvh,
    const float* __restrict__ pl2b, const float* __restrict__ pnw,
    const float* __restrict__ pnb)
{
    const int wv   = tid >> 6;
    const int lane = tid & 63;
    const int q    = lane & 31;
    const int half = lane >> 5;
    float X0 = 0.f, X1 = 0.f, X2 = 0.f;
    float B0 = 0.f, B1 = 0.f, B2 = 0.f;

    // ---------------- P1 ----------------
    if (wv >= 3) {
        for (int k = tid - 192; k < 2048; k += 832)
            s.wbuf[p ^ 1][k] = nw[k];
    } else {
        const int h = wv;
        float4 xa = s.x4[q];
        if (do_combine) {
            float f0 = sum4(s.fred[q][0]);
            float f1 = sum4(s.fred[q][1]);
            float f2 = sum4(s.fred[q][2]);
            ln3s(xa.x + f0 + pl2b[0], xa.y + f1 + pl2b[1],
                 xa.z + f2 + pl2b[2], pnw, pnb, X0, X1, X2);
        } else { X0 = xa.x; X1 = xa.y; X2 = xa.z; }
        if (lane < 32 && q < ntok) {
            s.kk[h][q] = sab[3+h] + saw[9+3*h]*X0  + saw[10+3*h]*X1 + saw[11+3*h]*X2;
            s.vv[h][q] = sab[6+h] + saw[18+3*h]*X0 + saw[19+3*h]*X1 + saw[20+3*h]*X2;
        }
        float qv = (sab[h] + saw[3*h]*X0 + saw[3*h+1]*X1 + saw[3*h+2]*X2) * LOG2E;
        float o = attn_half<MASK_SA>(qv, s.kk[h], s.vv[h], half, ntok, rep, repw);
        if (lane < 32 && q < ntok) s.oo[q][h] = o;
    }
    __syncthreads();   // bar1
    // ---------------- P2 ----------------
    if (wv >= 3) {
        for (int k = 2048 + tid - 192; k < 4096; k += 832)
            s.wbuf[p ^ 1][k] = nw[k];
    } else {
        const int h = wv;
        float o0 = s.oo[q][0], o1 = s.oo[q][1], o2 = s.oo[q][2];
        float y0 = X0 + saob[0] + saow[0]*o0 + saow[1]*o1 + saow[2]*o2;
        float y1 = X1 + saob[1] + saow[3]*o0 + saow[4]*o1 + saow[5]*o2;
        float y2 = X2 + saob[2] + saow[6]*o0 + saow[7]*o1 + saow[8]*o2;
        ln3s(y0, y1, y2, n1w, n1b, B0, B1, B2);
        if (!HAS_CA) {
            if (wv == 0 && lane < 32 && q < ntok)
                s.x4[q] = make_float4(B0, B1, B2, 0.f);
        } else {
            float cqv = (cab[h] + caw[3*h]*B0 + caw[3*h+1]*B1 + caw[3*h+2]*B2) * LOG2E;
            float oc = attn_half<false>(cqv, ckh + h*TT, cvh + h*TT, half, TT, -1, 1.f);
            if (lane < 32 && q < ntok) s.oo2[q][h] = oc;
        }
    }
    __syncthreads();   // bar2
    if (HAS_CA) {
        // ---------------- P3: wave0 CA out-proj + LN2 -> x4 ----------------
        if (wv == 0 && lane < 32 && q < ntok) {
            float c0 = s.oo2[q][0], c1 = s.oo2[q][1], c2 = s.oo2[q][2];
            float y0 = B0 + caob[0] + caow[0]*c0 + caow[1]*c1 + caow[2]*c2;
            float y1 = B1 + caob[1] + caow[3]*c0 + caow[4]*c1 + caow[5]*c2;
            float y2 = B2 + caob[2] + caow[6]*c0 + caow[7]*c1 + caow[8]*c2;
            float a0, a1, a2;
            ln3s(y0, y1, y2, n2w, n2b, a0, a1, a2);
            s.x4[q] = make_float4(a0, a1, a2, 0.f);
        }
        __syncthreads();   // bar3
    }
    // ---------------- P4: FFN (exact buckets) ----------------
    ffn_dispatch(s, tid, s.wbuf[p], ntok);
    __syncthreads();   // bar4
}

__global__ __launch_bounds__(1024, 4) void seq_kernel(
    const float* __restrict__ src, const float* __restrict__ angle,
    const float* __restrict__ enc_sa_w, const float* __restrict__ enc_sa_b,
    const float* __restrict__ enc_sa_ow, const float* __restrict__ enc_sa_ob,
    const float* __restrict__ enc_l2_b,
    const float* __restrict__ enc_n1_w, const float* __restrict__ enc_n1_b,
    const float* __restrict__ enc_n2_w, const float* __restrict__ enc_n2_b,
    const float* __restrict__ enc_nf_w, const float* __restrict__ enc_nf_b,
    const float* __restrict__ dec_sa_w, const float* __restrict__ dec_sa_b,
    const float* __restrict__ dec_sa_ow, const float* __restrict__ dec_sa_ob,
    const float* __restrict__ dec_ca_w, const float* __restrict__ dec_ca_b,
    const float* __restrict__ dec_ca_ow, const float* __restrict__ dec_ca_ob,
    const float* __restrict__ dec_l2_b,
    const float* __restrict__ dec_n1_w, const float* __restrict__ dec_n1_b,
    const float* __restrict__ dec_n2_w, const float* __restrict__ dec_n2_b,
    const float* __restrict__ dec_n3_w, const float* __restrict__ dec_n3_b,
    const float* __restrict__ dec_nf_w, const float* __restrict__ dec_nf_b,
    const float4* __restrict__ w_all,
    float* __restrict__ out)
{
    __shared__ SharedMem s;
    const int tid = threadIdx.x;
    const int b   = blockIdx.x;

    // ---- init: stage encoder layer 0 weights + build input
    for (int k = tid; k < 4096; k += 1024)
        s.wbuf[0][k] = w_all[k];
    if (tid < TT) {
        float x0 = src[b*64 + tid];
        float x1 = src[b*64 + 32 + tid];
        float x2 = angle[b];
        s.x4[tid] = make_float4(x0, x1, x2, 0.f);
        if (tid == 0) s.outst[0] = make_float4(x0, x1, x2, 0.f);
    }
    __syncthreads();

    int lp = 0;
    // ---- encoder
    for (int i = 0; i < NL; ++i) {
        const float4* nw = w_all + (size_t)((i < 11) ? (i + 1) : 12) * 4096;
        const int pi = (i > 0) ? (i - 1) : 0;
        run_layer<false, false>(s, tid, TT, -1, 1.f, i > 0, lp & 1, nw,
            enc_sa_w + i*27, enc_sa_b + i*9, enc_sa_ow + i*9, enc_sa_ob + i*3,
            enc_n1_w + i*3, enc_n1_b + i*3,
            nullptr, nullptr, nullptr, nullptr, nullptr, nullptr,
            nullptr, nullptr,
            enc_l2_b + pi*3, enc_n2_w + pi*3, enc_n2_b + pi*3);
        ++lp;
    }
    // encoder tail: combine layer 11 + final LN -> mem; rebuild x for step 1
    if (tid < 32) {
        float4 xa = s.x4[tid];
        float f0 = sum4(s.fred[tid][0]);
        float f1 = sum4(s.fred[tid][1]);
        float f2 = sum4(s.fred[tid][2]);
        float o0, o1, o2, m0, m1, m2;
        ln3s(xa.x + f0 + enc_l2_b[33], xa.y + f1 + enc_l2_b[34],
             xa.z + f2 + enc_l2_b[35], enc_n2_w + 33, enc_n2_b + 33, o0, o1, o2);
        ln3s(o0, o1, o2, enc_nf_w, enc_nf_b, m0, m1, m2);
        s.mem4[tid] = make_float4(m0, m1, m2, 0.f);
        s.x4[tid]   = (tid == 0) ? s.outst[0] : make_float4(0.f, 0.f, 0.f, 0.f);
    }
    __syncthreads();

    // ---- precompute cross-attn K,V for all decoder layers (head-major)
    for (int idx = tid; idx < NL * 96; idx += 1024) {
        const int lyr = idx / 96;
        const int r   = idx - lyr * 96;
        const int hh  = r >> 5;
        const int t   = r & 31;
        const float* w  = dec_ca_w + lyr*27;
        const float* bb = dec_ca_b + lyr*9;
        float4 mr = s.mem4[t];
        s.ck[lyr][hh][t] = bb[3+hh] + w[(3+hh)*3]*mr.x + w[(3+hh)*3+1]*mr.y + w[(3+hh)*3+2]*mr.z;
        s.cv[lyr][hh][t] = bb[6+hh] + w[(6+hh)*3]*mr.x + w[(6+hh)*3+1]*mr.y + w[(6+hh)*3+2]*mr.z;
    }
    __syncthreads();

    // ---- autoregressive decode with zero-token collapse:
    // tokens 0..t-1 real, token t = representative of 32-t identical zeros
    // (softmax multiplicity 32-t); pred[t] = representative output.
    for (int t = 1; t < TT; ++t) {
        const int ntok = t + 1;
        for (int i = 0; i < NL; ++i) {
            const float4* nw = w_all + (size_t)(12 + ((i < 11) ? (i + 1) : 0)) * 4096;
            const int pi = (i > 0) ? (i - 1) : 0;
            run_layer<true, true>(s, tid, ntok, t, (float)(TT - t), i > 0, lp & 1, nw,
                dec_sa_w + i*27, dec_sa_b + i*9, dec_sa_ow + i*9, dec_sa_ob + i*3,
                dec_n1_w + i*3, dec_n1_b + i*3,
                dec_ca_w + i*27, dec_ca_b + i*9, dec_ca_ow + i*9, dec_ca_ob + i*3,
                dec_n2_w + i*3, dec_n2_b + i*3,
                &s.ck[i][0][0], &s.cv[i][0][0],
                dec_l2_b + pi*3, dec_n3_w + pi*3, dec_n3_b + pi*3);
            ++lp;
        }
        // tail: combine layer 11 for token t -> outst[t]; rebuild x
        if (tid < 32) {
            if (tid == 0) {
                float4 xa = s.x4[t];
                float f0 = sum4(s.fred[t][0]);
                float f1 = sum4(s.fred[t][1]);
                float f2 = sum4(s.fred[t][2]);
                float o0, o1, o2, p0, p1, p2;
                ln3s(xa.x + f0 + dec_l2_b[33], xa.y + f1 + dec_l2_b[34],
                     xa.z + f2 + dec_l2_b[35], dec_n3_w + 33, dec_n3_b + 33,
                     o0, o1, o2);
                ln3s(o0, o1, o2, dec_nf_w, dec_nf_b, p0, p1, p2);
                s.outst[t] = make_float4(p0, p1, p2, 0.f);
            }
            s.x4[tid] = (tid <= t) ? s.outst[tid] : make_float4(0.f, 0.f, 0.f, 0.f);
        }
        __syncthreads();
    }

    // ---- write output: out[b, c, t]
    if (tid < TT) {
        float4 o = s.outst[tid];
        out[b*96 +  0 + tid] = o.x;
        out[b*96 + 32 + tid] = o.y;
        out[b*96 + 64 + tid] = o.z;
    }
}

extern "C" void kernel_launch(void* const* d_in, const int* in_sizes, int n_in,
                              void* d_out, int out_size, void* d_ws, size_t ws_size,
                              hipStream_t stream) {
    const float* src      = (const float*)d_in[0];
    const float* angle    = (const float*)d_in[1];
    const float* enc_sa_w = (const float*)d_in[2];
    const float* enc_sa_b = (const float*)d_in[3];
    const float* enc_sa_ow= (const float*)d_in[4];
    const float* enc_sa_ob= (const float*)d_in[5];
    const float* enc_l1_w = (const float*)d_in[6];
    const float* enc_l1_b = (const float*)d_in[7];
    const float* enc_l2_w = (const float*)d_in[8];
    const float* enc_l2_b = (const float*)d_in[9];
    const float* enc_n1_w = (const float*)d_in[10];
    const float* enc_n1_b = (const float*)d_in[11];
    const float* enc_n2_w = (const float*)d_in[12];
    const float* enc_n2_b = (const float*)d_in[13];
    const float* enc_nf_w = (const float*)d_in[14];
    const float* enc_nf_b = (const float*)d_in[15];
    const float* dec_sa_w = (const float*)d_in[16];
    const float* dec_sa_b = (const float*)d_in[17];
    const float* dec_sa_ow= (const float*)d_in[18];
    const float* dec_sa_ob= (const float*)d_in[19];
    const float* dec_ca_w = (const float*)d_in[20];
    const float* dec_ca_b = (const float*)d_in[21];
    const float* dec_ca_ow= (const float*)d_in[22];
    const float* dec_ca_ob= (const float*)d_in[23];
    const float* dec_l1_w = (const float*)d_in[24];
    const float* dec_l1_b = (const float*)d_in[25];
    const float* dec_l2_w = (const float*)d_in[26];
    const float* dec_l2_b = (const float*)d_in[27];
    const float* dec_n1_w = (const float*)d_in[28];
    const float* dec_n1_b = (const float*)d_in[29];
    const float* dec_n2_w = (const float*)d_in[30];
    const float* dec_n2_b = (const float*)d_in[31];
    const float* dec_n3_w = (const float*)d_in[32];
    const float* dec_n3_b = (const float*)d_in[33];
    const float* dec_nf_w = (const float*)d_in[34];
    const float* dec_nf_b = (const float*)d_in[35];

    float4* w_all = (float4*)d_ws;

    prepack_kernel<<<(24 * 1024 + 255) / 256, 256, 0, stream>>>(
        enc_l1_w, enc_l1_b, enc_l2_w,
        dec_l1_w, dec_l1_b, dec_l2_w,
        w_all);

    seq_kernel<<<NB, 1024, 0, stream>>>(
        src, angle,
        enc_sa_w, enc_sa_b, enc_sa_ow, enc_sa_ob, enc_l2_b,
        enc_n1_w, enc_n1_b, enc_n2_w, enc_n2_b, enc_nf_w, enc_nf_b,
        dec_sa_w, dec_sa_b, dec_sa_ow, dec_sa_ob,
        dec_ca_w, dec_ca_b, dec_ca_ow, dec_ca_ob, dec_l2_b,
        dec_n1_w, dec_n1_b, dec_n2_w, dec_n2_b, dec_n3_w, dec_n3_b,
        dec_nf_w, dec_nf_b,
        (const float4*)w_all,
        (float*)d_out);
}

// Round 14
// 1909.714 us; speedup vs baseline: 1.1344x; 1.1344x over previous
//
#include <hip/hip_runtime.h>
#include <math.h>

#define FF 2048
#define NL 12
#define NB 16
#define TT 32
#define EPS 1e-5f
#define LOG2E 1.44269504088896f

#if __has_builtin(__builtin_amdgcn_exp2f)
#define EXP2(x) __builtin_amdgcn_exp2f(x)
#else
#define EXP2(x) exp2f(x)
#endif

typedef float v2f __attribute__((ext_vector_type(2)));
__device__ __forceinline__ v2f mk2(float x){ v2f r; r.x = x; r.y = x; return r; }

// ---------------------------------------------------------------------------
// Prepack into d_ws as w_all[24][4096] float4, f-PAIRED for packed math:
//   [0..1023]    A0[fp] = {w0[2fp],w0[2fp+1], w1[2fp],w1[2fp+1]}
//   [1024..2047] A1[fp] = {w2[2fp],w2[2fp+1], b[2fp], b[2fp+1]}
//   [2048..3071] C0[fp] = {u0[2fp],u0[2fp+1], u1[2fp],u1[2fp+1]}
//   [3072..4095] C1[fp] = {u2[2fp],u2[2fp+1], 0, 0}
// ---------------------------------------------------------------------------
__global__ __launch_bounds__(256) void prepack_kernel(
    const float* __restrict__ enc_l1_w, const float* __restrict__ enc_l1_b,
    const float* __restrict__ enc_l2_w,
    const float* __restrict__ dec_l1_w, const float* __restrict__ dec_l1_b,
    const float* __restrict__ dec_l2_w,
    float4* __restrict__ w_all)
{
    int idx = blockIdx.x * blockDim.x + threadIdx.x;
    if (idx >= 24 * 1024) return;
    int lay = idx >> 10;
    int fp  = idx & 1023;
    int f0  = 2*fp, f1 = 2*fp + 1;
    const float *w1, *b1, *w2;
    if (lay < NL) {
        w1 = enc_l1_w + (size_t)lay * FF * 3;
        b1 = enc_l1_b + (size_t)lay * FF;
        w2 = enc_l2_w + (size_t)lay * 3 * FF;
    } else {
        int l = lay - NL;
        w1 = dec_l1_w + (size_t)l * FF * 3;
        b1 = dec_l1_b + (size_t)l * FF;
        w2 = dec_l2_w + (size_t)l * 3 * FF;
    }
    float4* base = w_all + (size_t)lay * 4096;
    base[fp]        = make_float4(w1[f0*3+0], w1[f1*3+0], w1[f0*3+1], w1[f1*3+1]);
    base[1024 + fp] = make_float4(w1[f0*3+2], w1[f1*3+2], b1[f0],     b1[f1]);
    base[2048 + fp] = make_float4(w2[f0],     w2[f1],     w2[FF+f0],  w2[FF+f1]);
    base[3072 + fp] = make_float4(w2[2*FF+f0], w2[2*FF+f1], 0.f, 0.f);
}

// ---------------------------------------------------------------------------
// Main kernel: one block per batch element, 1024 threads (16 waves).
// ---------------------------------------------------------------------------
struct __align__(16) SharedMem {
    float4 wbuf[2][4096];  // double-buffered layer weights (128 KB)
    float4 x4[TT];         // activations
    float4 fred[TT][3];    // FFN partials: [t][d] = 4 per-wave-group sums
    float4 outst[TT];      // decoder predictions
    float4 mem4[TT];       // encoder output
    float  kk[3][TT];      // self-attn keys, head-major
    float  vv[3][TT];      // self-attn values
    float4 oo[TT];         // SA attention outputs {h0,h1,h2,-}
    float4 oo2[TT];        // CA attention outputs {h0,h1,h2,-}
    float  ck[NL][3][TT];  // cross-attn keys per decoder layer
    float  cv[NL][3][TT];  // cross-attn values
};

__device__ __forceinline__ void ln3s(float y0, float y1, float y2,
    const float* __restrict__ w, const float* __restrict__ b,
    float& o0, float& o1, float& o2)
{
    float m  = (y0 + y1 + y2) * (1.0f / 3.0f);
    float d0 = y0 - m, d1 = y1 - m, d2 = y2 - m;
    float v  = (d0*d0 + d1*d1 + d2*d2) * (1.0f / 3.0f);
    float r  = __builtin_amdgcn_rsqf(v + EPS);
    o0 = d0 * r * w[0] + b[0];
    o1 = d1 * r * w[1] + b[1];
    o2 = d2 * r * w[2] + b[2];
}

template<int CTRL>
__device__ __forceinline__ float dpp_add(float v)
{
    int sh = __builtin_amdgcn_update_dpp(0, __float_as_int(v), CTRL, 0xF, 0xF, true);
    return v + __int_as_float(sh);
}

__device__ __forceinline__ float wave_sum64(float v)
{
    v = dpp_add<0x111>(v);
    v = dpp_add<0x112>(v);
    v = dpp_add<0x114>(v);
    v = dpp_add<0x118>(v);
    v = dpp_add<0x142>(v);
    v = dpp_add<0x143>(v);
    return v;   // valid in lane 63
}

__device__ __forceinline__ float sum4(float4 r)
{
    return (r.x + r.y) + (r.z + r.w);
}

// Halved-range softmax-attention: lanes 0-31 handle keys 0..15, lanes 32-63
// keys 16..31; partials combined via shfl_xor(32). qs has log2e folded.
// Split accumulators halve the serial fp-add chain.
template<bool MASK>
__device__ __forceinline__ float attn_half(float qs,
    const float* __restrict__ k, const float* __restrict__ v,
    int half, int ntok, int rep, float repw)
{
    const float4* k4 = (const float4*)k;
    const float4* v4 = (const float4*)v;
    float den0 = 0.f, den1 = 0.f, nv0 = 0.f, nv1 = 0.f;
    #pragma unroll
    for (int jb = 0; jb < 4; ++jb) {
        float4 kq = k4[half*4 + jb];
        float4 vq = v4[half*4 + jb];
        const float kj[4] = {kq.x, kq.y, kq.z, kq.w};
        const float vj[4] = {vq.x, vq.y, vq.z, vq.w};
        #pragma unroll
        for (int u = 0; u < 4; ++u) {
            float w = EXP2(qs * kj[u]);
            if (MASK) {
                const int j = half*16 + jb*4 + u;
                w = (j < ntok) ? w : 0.f;
                w = (j == rep) ? w * repw : w;
            }
            if (jb & 1) { den1 += w; nv1 = fmaf(w, vj[u], nv1); }
            else        { den0 += w; nv0 = fmaf(w, vj[u], nv0); }
        }
    }
    float den = den0 + den1;
    float nv  = nv0 + nv1;
    den += __shfl_xor(den, 32, 64);
    nv  += __shfl_xor(nv , 32, 64);
    return nv * __builtin_amdgcn_rcpf(den);
}

// FFN: 4 token groups x 256 f-lanes, 4 f-pairs per thread, packed fp32 math
// (v_pk_fma_f32), weights from LDS, DPP reduction + lane-63 store.
template<int NII>
__device__ __forceinline__ void ffn_body(SharedMem& s, int tid,
    const float4* __restrict__ wb)
{
    const int flane = tid & 255;
    const int g     = tid >> 8;
    const int w4    = (tid >> 6) & 3;
    const int lane  = tid & 63;
    const v2f z2 = {0.f, 0.f};
    float X0[NII], X1[NII], X2[NII];
    v2f ac0[NII], ac1[NII], ac2[NII];
    #pragma unroll
    for (int ii = 0; ii < NII; ++ii) {
        float4 xt = s.x4[g + 4*ii];
        X0[ii] = xt.x; X1[ii] = xt.y; X2[ii] = xt.z;
        ac0[ii] = z2; ac1[ii] = z2; ac2[ii] = z2;
    }
    #pragma unroll
    for (int jp = 0; jp < 4; ++jp) {
        const int fp = flane + 256*jp;
        float4 A0 = wb[fp], A1 = wb[1024+fp];
        float4 C0 = wb[2048+fp], C1 = wb[3072+fp];
        v2f ax = {A0.x, A0.y}, ay = {A0.z, A0.w};
        v2f az = {A1.x, A1.y}, ab = {A1.z, A1.w};
        v2f cx = {C0.x, C0.y}, cy = {C0.z, C0.w};
        v2f cz = {C1.x, C1.y};
        #pragma unroll
        for (int ii = 0; ii < NII; ++ii) {
            v2f h2 = __builtin_elementwise_fma(ax, mk2(X0[ii]),
                     __builtin_elementwise_fma(ay, mk2(X1[ii]),
                     __builtin_elementwise_fma(az, mk2(X2[ii]), ab)));
            h2 = __builtin_elementwise_max(h2, z2);
            ac0[ii] = __builtin_elementwise_fma(cx, h2, ac0[ii]);
            ac1[ii] = __builtin_elementwise_fma(cy, h2, ac1[ii]);
            ac2[ii] = __builtin_elementwise_fma(cz, h2, ac2[ii]);
        }
    }
    #pragma unroll
    for (int ii = 0; ii < NII; ++ii) {
        const int t = g + 4*ii;
        float r0 = wave_sum64(ac0[ii].x + ac0[ii].y);
        float r1 = wave_sum64(ac1[ii].x + ac1[ii].y);
        float r2 = wave_sum64(ac2[ii].x + ac2[ii].y);
        if (lane == 63) {
            ((float*)&s.fred[t][0])[w4] = r0;
            ((float*)&s.fred[t][1])[w4] = r1;
            ((float*)&s.fred[t][2])[w4] = r2;
        }
    }
}

// One transformer layer (R11 phase structure).
// P1: waves 0-2 combine+SA->oo | waves 3-15 prefetch half A.   barrier
// P2: waves 0-2 SA out-proj + LN1 -> B (redundant); if CA: CA -> oo2; else
//     wave0 writes x4. | waves 3-15 prefetch half B.           barrier
// P3 (CA only): wave0 CA out-proj + LN2 -> x4.                 barrier
// P4: FFN (all 16 waves).                                      barrier
template<bool HAS_CA, bool MASK_SA>
__device__ __forceinline__ void run_layer(SharedMem& s, int tid,
    int ntok, int rep, float repw, int do_combine, int p,
    const float4* __restrict__ nw,
    const float* __restrict__ saw, const float* __restrict__ sab,
    const float* __restrict__ saow, const float* __restrict__ saob,
    const float* __restrict__ n1w, const float* __restrict__ n1b,
    const float* __restrict__ caw, const float* __restrict__ cab,
    const float* __restrict__ caow, const float* __restrict__ caob,
    const float* __restrict__ n2w, const float* __restrict__ n2b,
    const float* __restrict__ ckh, const float* __restrict__ cvh,
    const float* __restrict__ pl2b, const float* __restrict__ pnw,
    const float* __restrict__ pnb)
{
    const int wv   = tid >> 6;
    const int lane = tid & 63;
    const int q    = lane & 31;
    const int half = lane >> 5;
    float X0 = 0.f, X1 = 0.f, X2 = 0.f;
    float B0 = 0.f, B1 = 0.f, B2 = 0.f;

    // ---------------- P1 ----------------
    if (wv >= 3) {
        for (int k = tid - 192; k < 2048; k += 832)
            s.wbuf[p ^ 1][k] = nw[k];
    } else {
        const int h = wv;
        float4 xa = s.x4[q];
        if (do_combine) {
            float f0 = sum4(s.fred[q][0]);
            float f1 = sum4(s.fred[q][1]);
            float f2 = sum4(s.fred[q][2]);
            ln3s(xa.x + f0 + pl2b[0], xa.y + f1 + pl2b[1],
                 xa.z + f2 + pl2b[2], pnw, pnb, X0, X1, X2);
        } else { X0 = xa.x; X1 = xa.y; X2 = xa.z; }
        if (lane < 32 && q < ntok) {
            s.kk[h][q] = sab[3+h] + saw[9+3*h]*X0  + saw[10+3*h]*X1 + saw[11+3*h]*X2;
            s.vv[h][q] = sab[6+h] + saw[18+3*h]*X0 + saw[19+3*h]*X1 + saw[20+3*h]*X2;
        }
        float qv = (sab[h] + saw[3*h]*X0 + saw[3*h+1]*X1 + saw[3*h+2]*X2) * LOG2E;
        float o = attn_half<MASK_SA>(qv, s.kk[h], s.vv[h], half, ntok, rep, repw);
        if (lane < 32 && q < ntok) ((float*)&s.oo[q])[h] = o;
    }
    __syncthreads();   // bar1
    // ---------------- P2 ----------------
    if (wv >= 3) {
        for (int k = 2048 + tid - 192; k < 4096; k += 832)
            s.wbuf[p ^ 1][k] = nw[k];
    } else {
        const int h = wv;
        float4 ov = s.oo[q];
        float y0 = X0 + saob[0] + saow[0]*ov.x + saow[1]*ov.y + saow[2]*ov.z;
        float y1 = X1 + saob[1] + saow[3]*ov.x + saow[4]*ov.y + saow[5]*ov.z;
        float y2 = X2 + saob[2] + saow[6]*ov.x + saow[7]*ov.y + saow[8]*ov.z;
        ln3s(y0, y1, y2, n1w, n1b, B0, B1, B2);
        if (!HAS_CA) {
            if (wv == 0 && lane < 32 && q < ntok)
                s.x4[q] = make_float4(B0, B1, B2, 0.f);
        } else {
            float cqv = (cab[h] + caw[3*h]*B0 + caw[3*h+1]*B1 + caw[3*h+2]*B2) * LOG2E;
            float oc = attn_half<false>(cqv, ckh + h*TT, cvh + h*TT, half, TT, -1, 1.f);
            if (lane < 32 && q < ntok) ((float*)&s.oo2[q])[h] = oc;
        }
    }
    __syncthreads();   // bar2
    if (HAS_CA) {
        // ---------------- P3: wave0 CA out-proj + LN2 -> x4 ----------------
        if (wv == 0 && lane < 32 && q < ntok) {
            float4 cv2 = s.oo2[q];
            float y0 = B0 + caob[0] + caow[0]*cv2.x + caow[1]*cv2.y + caow[2]*cv2.z;
            float y1 = B1 + caob[1] + caow[3]*cv2.x + caow[4]*cv2.y + caow[5]*cv2.z;
            float y2 = B2 + caob[2] + caow[6]*cv2.x + caow[7]*cv2.y + caow[8]*cv2.z;
            float a0, a1, a2;
            ln3s(y0, y1, y2, n2w, n2b, a0, a1, a2);
            s.x4[q] = make_float4(a0, a1, a2, 0.f);
        }
        __syncthreads();   // bar3
    }
    // ---------------- P4: FFN ----------------
    const float4* wb = s.wbuf[p];
    if (ntok <= 8)       ffn_body<2>(s, tid, wb);
    else if (ntok <= 16) ffn_body<4>(s, tid, wb);
    else                 ffn_body<8>(s, tid, wb);
    __syncthreads();   // bar4
}

__global__ __launch_bounds__(1024, 4) void seq_kernel(
    const float* __restrict__ src, const float* __restrict__ angle,
    const float* __restrict__ enc_sa_w, const float* __restrict__ enc_sa_b,
    const float* __restrict__ enc_sa_ow, const float* __restrict__ enc_sa_ob,
    const float* __restrict__ enc_l2_b,
    const float* __restrict__ enc_n1_w, const float* __restrict__ enc_n1_b,
    const float* __restrict__ enc_n2_w, const float* __restrict__ enc_n2_b,
    const float* __restrict__ enc_nf_w, const float* __restrict__ enc_nf_b,
    const float* __restrict__ dec_sa_w, const float* __restrict__ dec_sa_b,
    const float* __restrict__ dec_sa_ow, const float* __restrict__ dec_sa_ob,
    const float* __restrict__ dec_ca_w, const float* __restrict__ dec_ca_b,
    const float* __restrict__ dec_ca_ow, const float* __restrict__ dec_ca_ob,
    const float* __restrict__ dec_l2_b,
    const float* __restrict__ dec_n1_w, const float* __restrict__ dec_n1_b,
    const float* __restrict__ dec_n2_w, const float* __restrict__ dec_n2_b,
    const float* __restrict__ dec_n3_w, const float* __restrict__ dec_n3_b,
    const float* __restrict__ dec_nf_w, const float* __restrict__ dec_nf_b,
    const float4* __restrict__ w_all,
    float* __restrict__ out)
{
    __shared__ SharedMem s;
    const int tid = threadIdx.x;
    const int b   = blockIdx.x;

    // ---- init: stage encoder layer 0 weights + build input
    for (int k = tid; k < 4096; k += 1024)
        s.wbuf[0][k] = w_all[k];
    if (tid < TT) {
        float x0 = src[b*64 + tid];
        float x1 = src[b*64 + 32 + tid];
        float x2 = angle[b];
        s.x4[tid] = make_float4(x0, x1, x2, 0.f);
        if (tid == 0) s.outst[0] = make_float4(x0, x1, x2, 0.f);
    }
    __syncthreads();

    int lp = 0;
    // ---- encoder
    for (int i = 0; i < NL; ++i) {
        const float4* nw = w_all + (size_t)((i < 11) ? (i + 1) : 12) * 4096;
        const int pi = (i > 0) ? (i - 1) : 0;
        run_layer<false, false>(s, tid, TT, -1, 1.f, i > 0, lp & 1, nw,
            enc_sa_w + i*27, enc_sa_b + i*9, enc_sa_ow + i*9, enc_sa_ob + i*3,
            enc_n1_w + i*3, enc_n1_b + i*3,
            nullptr, nullptr, nullptr, nullptr, nullptr, nullptr,
            nullptr, nullptr,
            enc_l2_b + pi*3, enc_n2_w + pi*3, enc_n2_b + pi*3);
        ++lp;
    }
    // encoder tail: combine layer 11 + final LN -> mem; rebuild x for step 1
    if (tid < 32) {
        float4 xa = s.x4[tid];
        float f0 = sum4(s.fred[tid][0]);
        float f1 = sum4(s.fred[tid][1]);
        float f2 = sum4(s.fred[tid][2]);
        float o0, o1, o2, m0, m1, m2;
        ln3s(xa.x + f0 + enc_l2_b[33], xa.y + f1 + enc_l2_b[34],
             xa.z + f2 + enc_l2_b[35], enc_n2_w + 33, enc_n2_b + 33, o0, o1, o2);
        ln3s(o0, o1, o2, enc_nf_w, enc_nf_b, m0, m1, m2);
        s.mem4[tid] = make_float4(m0, m1, m2, 0.f);
        s.x4[tid]   = (tid == 0) ? s.outst[0] : make_float4(0.f, 0.f, 0.f, 0.f);
    }
    __syncthreads();

    // ---- precompute cross-attn K,V for all decoder layers (head-major)
    for (int idx = tid; idx < NL * 96; idx += 1024) {
        const int lyr = idx / 96;
        const int r   = idx - lyr * 96;
        const int hh  = r >> 5;
        const int t   = r & 31;
        const float* w  = dec_ca_w + lyr*27;
        const float* bb = dec_ca_b + lyr*9;
        float4 mr = s.mem4[t];
        s.ck[lyr][hh][t] = bb[3+hh] + w[(3+hh)*3]*mr.x + w[(3+hh)*3+1]*mr.y + w[(3+hh)*3+2]*mr.z;
        s.cv[lyr][hh][t] = bb[6+hh] + w[(6+hh)*3]*mr.x + w[(6+hh)*3+1]*mr.y + w[(6+hh)*3+2]*mr.z;
    }
    __syncthreads();

    // ---- autoregressive decode with zero-token collapse:
    // tokens 0..t-1 real, token t = representative of 32-t identical zeros
    // (softmax multiplicity 32-t); pred[t] = representative output.
    for (int t = 1; t < TT; ++t) {
        const int ntok = t + 1;
        for (int i = 0; i < NL; ++i) {
            const float4* nw = w_all + (size_t)(12 + ((i < 11) ? (i + 1) : 0)) * 4096;
            const int pi = (i > 0) ? (i - 1) : 0;
            run_layer<true, true>(s, tid, ntok, t, (float)(TT - t), i > 0, lp & 1, nw,
                dec_sa_w + i*27, dec_sa_b + i*9, dec_sa_ow + i*9, dec_sa_ob + i*3,
                dec_n1_w + i*3, dec_n1_b + i*3,
                dec_ca_w + i*27, dec_ca_b + i*9, dec_ca_ow + i*9, dec_ca_ob + i*3,
                dec_n2_w + i*3, dec_n2_b + i*3,
                &s.ck[i][0][0], &s.cv[i][0][0],
                dec_l2_b + pi*3, dec_n3_w + pi*3, dec_n3_b + pi*3);
            ++lp;
        }
        // tail: combine layer 11 for token t -> outst[t]; rebuild x
        if (tid < 32) {
            if (tid == 0) {
                float4 xa = s.x4[t];
                float f0 = sum4(s.fred[t][0]);
                float f1 = sum4(s.fred[t][1]);
                float f2 = sum4(s.fred[t][2]);
                float o0, o1, o2, p0, p1, p2;
                ln3s(xa.x + f0 + dec_l2_b[33], xa.y + f1 + dec_l2_b[34],
                     xa.z + f2 + dec_l2_b[35], dec_n3_w + 33, dec_n3_b + 33,
                     o0, o1, o2);
                ln3s(o0, o1, o2, dec_nf_w, dec_nf_b, p0, p1, p2);
                s.outst[t] = make_float4(p0, p1, p2, 0.f);
            }
            s.x4[tid] = (tid <= t) ? s.outst[tid] : make_float4(0.f, 0.f, 0.f, 0.f);
        }
        __syncthreads();
    }

    // ---- write output: out[b, c, t]
    if (tid < TT) {
        float4 o = s.outst[tid];
        out[b*96 +  0 + tid] = o.x;
        out[b*96 + 32 + tid] = o.y;
        out[b*96 + 64 + tid] = o.z;
    }
}

extern "C" void kernel_launch(void* const* d_in, const int* in_sizes, int n_in,
                              void* d_out, int out_size, void* d_ws, size_t ws_size,
                              hipStream_t stream) {
    const float* src      = (const float*)d_in[0];
    const float* angle    = (const float*)d_in[1];
    const float* enc_sa_w = (const float*)d_in[2];
    const float* enc_sa_b = (const float*)d_in[3];
    const float* enc_sa_ow= (const float*)d_in[4];
    const float* enc_sa_ob= (const float*)d_in[5];
    const float* enc_l1_w = (const float*)d_in[6];
    const float* enc_l1_b = (const float*)d_in[7];
    const float* enc_l2_w = (const float*)d_in[8];
    const float* enc_l2_b = (const float*)d_in[9];
    const float* enc_n1_w = (const float*)d_in[10];
    const float* enc_n1_b = (const float*)d_in[11];
    const float* enc_n2_w = (const float*)d_in[12];
    const float* enc_n2_b = (const float*)d_in[13];
    const float* enc_nf_w = (const float*)d_in[14];
    const float* enc_nf_b = (const float*)d_in[15];
    const float* dec_sa_w = (const float*)d_in[16];
    const float* dec_sa_b = (const float*)d_in[17];
    const float* dec_sa_ow= (const float*)d_in[18];
    const float* dec_sa_ob= (const float*)d_in[19];
    const float* dec_ca_w = (const float*)d_in[20];
    const float* dec_ca_b = (const float*)d_in[21];
    const float* dec_ca_ow= (const float*)d_in[22];
    const float* dec_ca_ob= (const float*)d_in[23];
    const float* dec_l1_w = (const float*)d_in[24];
    const float* dec_l1_b = (const float*)d_in[25];
    const float* dec_l2_w = (const float*)d_in[26];
    const float* dec_l2_b = (const float*)d_in[27];
    const float* dec_n1_w = (const float*)d_in[28];
    const float* dec_n1_b = (const float*)d_in[29];
    const float* dec_n2_w = (const float*)d_in[30];
    const float* dec_n2_b = (const float*)d_in[31];
    const float* dec_n3_w = (const float*)d_in[32];
    const float* dec_n3_b = (const float*)d_in[33];
    const float* dec_nf_w = (const float*)d_in[34];
    const float* dec_nf_b = (const float*)d_in[35];

    float4* w_all = (float4*)d_ws;

    prepack_kernel<<<(24 * 1024 + 255) / 256, 256, 0, stream>>>(
        enc_l1_w, enc_l1_b, enc_l2_w,
        dec_l1_w, dec_l1_b, dec_l2_w,
        w_all);

    seq_kernel<<<NB, 1024, 0, stream>>>(
        src, angle,
        enc_sa_w, enc_sa_b, enc_sa_ow, enc_sa_ob, enc_l2_b,
        enc_n1_w, enc_n1_b, enc_n2_w, enc_n2_b, enc_nf_w, enc_nf_b,
        dec_sa_w, dec_sa_b, dec_sa_ow, dec_sa_ob,
        dec_ca_w, dec_ca_b, dec_ca_ow, dec_ca_ob, dec_l2_b,
        dec_n1_w, dec_n1_b, dec_n2_w, dec_n2_b, dec_n3_w, dec_n3_b,
        dec_nf_w, dec_nf_b,
        (const float4*)w_all,
        (float*)d_out);
}